// Round 1
// baseline (1944.504 us; speedup 1.0000x reference)
//
#include <hip/hip_runtime.h>

typedef unsigned short u16;
typedef __attribute__((ext_vector_type(8))) __bf16 bf16x8;
typedef __attribute__((ext_vector_type(4))) float f32x4;

__device__ __forceinline__ float bf2f(u16 u) { return __uint_as_float(((unsigned)u) << 16); }
__device__ __forceinline__ u16 f2bf(float f) {
    unsigned x = __float_as_uint(f);
    x += 0x7fffu + ((x >> 16) & 1u);
    return (u16)(x >> 16);
}

// ---------------------------------------------------------------------------
// Generic GEMM: C[M,N] = A[M,K] * B[N,K]^T   (bf16 in, fp32 acc)
// epilogue: optional bias[M], act (0 none, 1 prelu(*alpha), 2 relu),
//           optional residual[M,N] (fp32), optional fp32 out [M,N],
//           optional transposed bf16 out [N, ldT].
// Block tile 128x128, BK=32, 256 threads (4 waves, each 64x64).
// ---------------------------------------------------------------------------
__global__ __launch_bounds__(256) void d7_gemm(
    const u16* __restrict__ A, const u16* __restrict__ B,
    int M, int N, int K,
    const float* __restrict__ bias, const float* __restrict__ alpha, int act,
    const float* __restrict__ resid,
    float* __restrict__ outF, u16* __restrict__ outT, int ldT)
{
    __shared__ u16 As[128 * 40];   // +8 pad per 32-wide row: 80B stride breaks 8-way conflicts
    __shared__ u16 Bs[128 * 40];

    const int tid = threadIdx.x;
    const int w = tid >> 6, lane = tid & 63;
    const int wm = w >> 1, wn = w & 1;
    const int bn = blockIdx.x, bm = blockIdx.y;

    // staging: thread covers 32B (16 elements) of one row; 2 threads per row
    const int srow = tid >> 1;
    const int soff = (tid & 1) * 16;
    const u16* gA = A + (size_t)(bm * 128 + srow) * K + soff;
    const u16* gB = B + (size_t)(bn * 128 + srow) * K + soff;
    u16* lA = &As[srow * 40 + soff];
    u16* lB = &Bs[srow * 40 + soff];

    f32x4 acc[4][4] = {};

    for (int k0 = 0; k0 < K; k0 += 32) {
        __syncthreads();
        ((uint4*)lA)[0] = ((const uint4*)gA)[0];
        ((uint4*)lA)[1] = ((const uint4*)gA)[1];
        ((uint4*)lB)[0] = ((const uint4*)gB)[0];
        ((uint4*)lB)[1] = ((const uint4*)gB)[1];
        gA += 32; gB += 32;
        __syncthreads();

        bf16x8 a[4], b[4];
        #pragma unroll
        for (int mt = 0; mt < 4; ++mt)
            a[mt] = *reinterpret_cast<const bf16x8*>(&As[(wm * 64 + mt * 16 + (lane & 15)) * 40 + (lane >> 4) * 8]);
        #pragma unroll
        for (int nt = 0; nt < 4; ++nt)
            b[nt] = *reinterpret_cast<const bf16x8*>(&Bs[(wn * 64 + nt * 16 + (lane & 15)) * 40 + (lane >> 4) * 8]);
        #pragma unroll
        for (int mt = 0; mt < 4; ++mt)
            #pragma unroll
            for (int nt = 0; nt < 4; ++nt)
                acc[mt][nt] = __builtin_amdgcn_mfma_f32_16x16x32_bf16(a[mt], b[nt], acc[mt][nt], 0, 0, 0);
    }

    const float aval = (act == 1) ? alpha[0] : 0.0f;
    #pragma unroll
    for (int mt = 0; mt < 4; ++mt) {
        const int mg = bm * 128 + wm * 64 + mt * 16 + ((lane >> 4) << 2);
        float bv[4] = {0.f, 0.f, 0.f, 0.f};
        if (bias) {
            #pragma unroll
            for (int r = 0; r < 4; ++r) bv[r] = bias[mg + r];
        }
        #pragma unroll
        for (int nt = 0; nt < 4; ++nt) {
            const int ng = bn * 128 + wn * 64 + nt * 16 + (lane & 15);
            float v[4];
            #pragma unroll
            for (int r = 0; r < 4; ++r) {
                float t = acc[mt][nt][r] + bv[r];
                if (act == 1) t = (t >= 0.f) ? t : aval * t;
                else if (act == 2) t = fmaxf(t, 0.f);
                if (resid) t += resid[(size_t)(mg + r) * N + ng];
                v[r] = t;
            }
            if (outF) {
                #pragma unroll
                for (int r = 0; r < 4; ++r) outF[(size_t)(mg + r) * N + ng] = v[r];
            }
            if (outT) {
                unsigned long long pk = (unsigned long long)f2bf(v[0])
                    | ((unsigned long long)f2bf(v[1]) << 16)
                    | ((unsigned long long)f2bf(v[2]) << 32)
                    | ((unsigned long long)f2bf(v[3]) << 48);
                *reinterpret_cast<unsigned long long*>(outT + (size_t)ng * ldT + mg) = pk;
            }
        }
    }
}

// ---------------------------------------------------------------------------
// small helpers
// ---------------------------------------------------------------------------
__global__ __launch_bounds__(256) void d7_cast(const float* __restrict__ src, u16* __restrict__ dst, int n) {
    int i = blockIdx.x * 256 + threadIdx.x;
    if (i < n) dst[i] = f2bf(src[i]);
}

__global__ __launch_bounds__(256) void d7_maxpool(const float* __restrict__ x, float* __restrict__ out) {
    int p = blockIdx.x * 256 + threadIdx.x;       // 4096
    int c = blockIdx.y, b = blockIdx.z;
    int oh = p >> 6, ow = p & 63;
    const float* ip = x + ((size_t)b * 64 + c) * 16384;
    float v0 = ip[(2 * oh) * 128 + 2 * ow];
    float v1 = ip[(2 * oh) * 128 + 2 * ow + 1];
    float v2 = ip[(2 * oh + 1) * 128 + 2 * ow];
    float v3 = ip[(2 * oh + 1) * 128 + 2 * ow + 1];
    out[((size_t)b * 64 + c) * 4096 + p] = fmaxf(fmaxf(v0, v1), fmaxf(v2, v3));
}

// im2colT: img [Cin][64][64] fp32 -> patT [4096][Cin*9] bf16, k = c*9 + i*3 + j
__global__ __launch_bounds__(256) void d7_im2col(const float* __restrict__ img, u16* __restrict__ patT, int Cin) {
    int K = Cin * 9;
    int k = blockIdx.x * 256 + threadIdx.x;
    if (k >= K) return;
    int p = blockIdx.y;
    int c = k / 9, k9 = k - c * 9;
    int h = p >> 6, w = p & 63;
    int y = h + k9 / 3 - 1, x = w + (k9 % 3) - 1;
    float v = (y >= 0 && y < 64 && x >= 0 && x < 64) ? img[(size_t)c * 4096 + y * 64 + x] : 0.f;
    patT[(size_t)p * K + k] = f2bf(v);
}

// 1x1 conv + prelu: in [b][Cin][P] -> out [b][Cout][P]
__global__ __launch_bounds__(256) void d7_conv1x1(
    const float* __restrict__ in, const float* __restrict__ W,
    const float* __restrict__ bias, const float* __restrict__ alpha,
    float* __restrict__ out, int Cin, int P, long in_bs, long out_bs)
{
    int p = blockIdx.x * 256 + threadIdx.x;
    if (p >= P) return;
    int co = blockIdx.y, b = blockIdx.z;
    const float* ip = in + (size_t)b * in_bs;
    float acc = bias[co];
    for (int ci = 0; ci < Cin; ++ci) acc += W[co * Cin + ci] * ip[(size_t)ci * P + p];
    float a = alpha[0];
    out[(size_t)b * out_bs + (size_t)co * P + p] = (acc >= 0.f) ? acc : a * acc;
}

// jax.image.resize bilinear antialias=True, 64 -> OS
template <int OS>
__device__ __forceinline__ void d7_taps(int o, int& i0, float w3[3]) {
    const float inv = 64.0f / OS;       // kernel_scale = inv_scale (>1, antialias)
    float s = (o + 0.5f) * inv - 0.5f;
    i0 = (int)ceilf(s - inv);
    float wsum = 0.f;
    #pragma unroll
    for (int t = 0; t < 3; ++t) {
        int y = i0 + t;
        float wt = 1.0f - fabsf((float)y - s) / inv;
        wt = (wt > 0.f && y >= 0 && y < 64) ? wt : 0.f;
        w3[t] = wt; wsum += wt;
    }
    float r = 1.0f / wsum;
    w3[0] *= r; w3[1] *= r; w3[2] *= r;
}

template <int OS>
__global__ __launch_bounds__(256) void d7_resize(const float* __restrict__ in, float* __restrict__ out, long out_bs) {
    int p = blockIdx.x * 256 + threadIdx.x;
    if (p >= OS * OS) return;
    int c = blockIdx.y, b = blockIdx.z;
    int oh = p / OS, ow = p - oh * OS;
    const float* img = in + ((size_t)b * 128 + c) * 4096;
    int y0, x0; float wy[3], wx[3];
    d7_taps<OS>(oh, y0, wy);
    d7_taps<OS>(ow, x0, wx);
    float sum = 0.f;
    #pragma unroll
    for (int iy = 0; iy < 3; ++iy) {
        if (wy[iy] <= 0.f) continue;
        float rs = 0.f;
        #pragma unroll
        for (int ix = 0; ix < 3; ++ix) {
            if (wx[ix] <= 0.f) continue;
            rs += wx[ix] * img[(y0 + iy) * 64 + (x0 + ix)];
        }
        sum += wy[iy] * rs;
    }
    out[(size_t)b * out_bs + (size_t)c * OS * OS + p] = sum;
}

__device__ __forceinline__ void d7_scale_lookup(int l, int& hs, int& ws_, int& HS, int& off) {
    if (l < 4096)      { int li = l;        HS = 64; hs = li >> 6; ws_ = li & 63;   off = 0; }
    else if (l < 7345) { int li = l - 4096; HS = 57; hs = li / 57; ws_ = li % 57;   off = 4096; }
    else if (l < 9946) { int li = l - 7345; HS = 51; hs = li / 51; ws_ = li % 51;   off = 7345; }
    else               { int li = l - 9946; HS = 44; hs = li / 44; ws_ = li % 44;   off = 9946; }
}

// wn: refm (concat per-scale [64][HS*HS] blocks at off*64) -> wn [11904][576] bf16, normalized
__global__ __launch_bounds__(256) void d7_wn(const float* __restrict__ refm, u16* __restrict__ wn) {
    int w = threadIdx.x >> 6, lane = threadIdx.x & 63;
    int l = blockIdx.x * 4 + w;
    u16* wr = wn + (size_t)l * 576 + lane * 9;
    if (l >= 11882) {
        #pragma unroll
        for (int kk = 0; kk < 9; ++kk) wr[kk] = 0;
        return;
    }
    int hs, ws_, HS, off;
    d7_scale_lookup(l, hs, ws_, HS, off);
    const float* img = refm + (size_t)off * 64 + (size_t)lane * HS * HS;
    float v[9]; float ss = 0.f;
    #pragma unroll
    for (int ii = 0; ii < 3; ++ii)
        #pragma unroll
        for (int jj = 0; jj < 3; ++jj) {
            int y = hs + ii - 1, x = ws_ + jj - 1;
            float t = (y >= 0 && y < HS && x >= 0 && x < HS) ? img[y * HS + x] : 0.f;
            v[ii * 3 + jj] = t; ss += t * t;
        }
    #pragma unroll
    for (int o = 1; o < 64; o <<= 1) ss += __shfl_xor(ss, o);
    float inv = 1.0f / fmaxf(sqrtf(ss), 1e-4f);
    #pragma unroll
    for (int kk = 0; kk < 9; ++kk) wr[kk] = f2bf(v[kk] * inv);
}

// rwP [m=(i*3+j)*128+c][l] = base[c, hs+1-i, ws+1-j]  (zero OOB / pad)
__global__ __launch_bounds__(256) void d7_rwp(const float* __restrict__ base, u16* __restrict__ rwp) {
    int l = blockIdx.x * 256 + threadIdx.x;
    if (l >= 11904) return;
    int mrow = blockIdx.y;
    int k9 = mrow >> 7, c = mrow & 127;
    int i = k9 / 3, j = k9 - i * 3;
    float v = 0.f;
    if (l < 11882) {
        int hs, ws_, HS, off;
        d7_scale_lookup(l, hs, ws_, HS, off);
        int y = hs + 1 - i, x = ws_ + 1 - j;
        if (y >= 0 && y < HS && x >= 0 && x < HS)
            v = base[(size_t)off * 128 + (size_t)c * HS * HS + y * HS + x];
    }
    rwp[(size_t)mrow * 11904 + l] = f2bf(v);
}

// softmax over l (11882 real, 11904 padded) in-place on bf16 scoresT [4096][11904]
__global__ __launch_bounds__(256) void d7_softmax(u16* __restrict__ sc) {
    const int LT = 11882, LTP = 11904, NI = 47;
    int p = blockIdx.x, tid = threadIdx.x, w = tid >> 6, lane = tid & 63;
    u16* row = sc + (size_t)p * LTP;
    float vals[NI];
    float m = -1e30f;
    #pragma unroll
    for (int j = 0; j < NI; ++j) {
        int l = tid + j * 256;
        float v = (l < LT) ? bf2f(row[l]) : -1e30f;
        vals[j] = v; m = fmaxf(m, v);
    }
    #pragma unroll
    for (int o = 1; o < 64; o <<= 1) m = fmaxf(m, __shfl_xor(m, o));
    __shared__ float red[4];
    if (lane == 0) red[w] = m;
    __syncthreads();
    m = fmaxf(fmaxf(red[0], red[1]), fmaxf(red[2], red[3]));
    __syncthreads();
    float s = 0.f;
    #pragma unroll
    for (int j = 0; j < NI; ++j) {
        float e = __expf((vals[j] - m) * 10.0f);
        vals[j] = e; s += e;
    }
    #pragma unroll
    for (int o = 1; o < 64; o <<= 1) s += __shfl_xor(s, o);
    if (lane == 0) red[w] = s;
    __syncthreads();
    float invZ = 1.0f / (red[0] + red[1] + red[2] + red[3]);
    #pragma unroll
    for (int j = 0; j < NI; ++j) {
        int l = tid + j * 256;
        if (l < LTP) row[l] = f2bf(vals[j] * invZ);
    }
}

// out_pa[c,p] = resid[c,p] + 0.25 * sum_{i,j} Q[(i*3+j)*128+c, shifted p]
__global__ __launch_bounds__(256) void d7_shiftadd(const float* __restrict__ Q, const float* __restrict__ resid,
                                                   float* __restrict__ out) {
    int p = blockIdx.x * 256 + threadIdx.x;   // 4096
    int c = blockIdx.y;
    int h = p >> 6, w = p & 63;
    float s = 0.f;
    #pragma unroll
    for (int i = 0; i < 3; ++i) {
        int y = h + i - 1;
        if (y < 0 || y >= 64) continue;
        #pragma unroll
        for (int j = 0; j < 3; ++j) {
            int x = w + j - 1;
            if (x < 0 || x >= 64) continue;
            s += Q[((size_t)(i * 3 + j) * 128 + c) * 4096 + y * 64 + x];
        }
    }
    out[(size_t)c * 4096 + p] = resid[(size_t)c * 4096 + p] + 0.25f * s;
}

// ---------------------------------------------------------------------------
extern "C" void kernel_launch(void* const* d_in, const int* in_sizes, int n_in,
                              void* d_out, int out_size, void* d_ws, size_t ws_size,
                              hipStream_t stream) {
    const float* x      = (const float*)d_in[0];
    const float* bb0_w  = (const float*)d_in[1];
    const float* bb0_b  = (const float*)d_in[2];
    const float* bb0_a  = (const float*)d_in[3];
    const float* rb1_w1 = (const float*)d_in[4];
    const float* rb1_b1 = (const float*)d_in[5];
    const float* rb1_w2 = (const float*)d_in[6];
    const float* rb1_b2 = (const float*)d_in[7];
    const float* pamb_w = (const float*)d_in[8];
    const float* pamb_b = (const float*)d_in[9];
    const float* pamb_a = (const float*)d_in[10];
    const float* pam_w  = (const float*)d_in[11];
    const float* pam_b  = (const float*)d_in[12];
    const float* pam_a  = (const float*)d_in[13];
    const float* paa_w  = (const float*)d_in[14];
    const float* paa_b  = (const float*)d_in[15];
    const float* paa_a  = (const float*)d_in[16];
    const float* rb2_w1 = (const float*)d_in[17];
    const float* rb2_b1 = (const float*)d_in[18];
    const float* rb2_w2 = (const float*)d_in[19];
    const float* rb2_b2 = (const float*)d_in[20];
    float* out = (float*)d_out;
    (void)in_sizes; (void)n_in; (void)out_size; (void)ws_size;

    char* wp = (char*)d_ws;
    auto alloc = [&](size_t nbytes) { void* p = wp; wp += (nbytes + 255) & ~(size_t)255; return p; };
    float* h0f   = (float*)alloc(2ull * 64 * 4096 * 4);
    float* h1f   = (float*)alloc(2ull * 128 * 4096 * 4);
    float* h2f   = (float*)alloc(2ull * 128 * 4096 * 4);
    float* paf   = (float*)alloc(2ull * 128 * 4096 * 4);
    float* tbuf  = (float*)alloc(2ull * 128 * 4096 * 4);
    float* refb  = (float*)alloc(2ull * 128 * 7786 * 4);
    float* mbb   = (float*)alloc(2ull * 64 * 4096 * 4);
    float* refm  = (float*)alloc(2ull * 64 * 11882 * 4);
    float* baseb = (float*)alloc(2ull * 128 * 11882 * 4);
    u16* wnb     = (u16*)alloc(11904ull * 576 * 2);
    u16* rwpb    = (u16*)alloc(1152ull * 11904 * 2);
    u16* scT     = (u16*)alloc(4096ull * 11904 * 2);
    float* Qb    = (float*)alloc(1152ull * 4096 * 4);
    u16* patT    = (u16*)alloc(4096ull * 1152 * 2);
    u16* A0      = (u16*)alloc(73728ull * 2);
    u16* A1      = (u16*)alloc(147456ull * 2);
    u16* A2      = (u16*)alloc(147456ull * 2);
    u16* A3      = (u16*)alloc(147456ull * 2);
    u16* A4      = (u16*)alloc(147456ull * 2);

    auto gemm = [&](const u16* A, const u16* B, int M, int K,
                    const float* bias, const float* alpha, int act,
                    const float* resid, float* oF, u16* oT, int ldT) {
        d7_gemm<<<dim3(32, M / 128), 256, 0, stream>>>(A, B, M, 4096, K, bias, alpha, act, resid, oF, oT, ldT);
    };

    // weight casts (layouts already [co][ci*9+k9])
    d7_cast<<<dim3(288), 256, 0, stream>>>(bb0_w, A0, 73728);
    d7_cast<<<dim3(576), 256, 0, stream>>>(rb1_w1, A1, 147456);
    d7_cast<<<dim3(576), 256, 0, stream>>>(rb1_w2, A2, 147456);
    d7_cast<<<dim3(576), 256, 0, stream>>>(rb2_w1, A3, 147456);
    d7_cast<<<dim3(576), 256, 0, stream>>>(rb2_w2, A4, 147456);

    d7_maxpool<<<dim3(16, 64, 2), 256, 0, stream>>>(x, h0f);

    // BasicBlock: conv3x3 64->128 + bias + prelu
    for (int b = 0; b < 2; ++b) {
        d7_im2col<<<dim3(3, 4096), 256, 0, stream>>>(h0f + (size_t)b * 64 * 4096, patT, 64);
        gemm(A0, patT, 128, 576, bb0_b, bb0_a, 1, nullptr, h1f + (size_t)b * 128 * 4096, nullptr, 0);
    }
    // ResBlock1
    for (int b = 0; b < 2; ++b) {
        d7_im2col<<<dim3(5, 4096), 256, 0, stream>>>(h1f + (size_t)b * 128 * 4096, patT, 128);
        gemm(A1, patT, 128, 1152, rb1_b1, nullptr, 2, nullptr, tbuf + (size_t)b * 128 * 4096, nullptr, 0);
    }
    for (int b = 0; b < 2; ++b) {
        d7_im2col<<<dim3(5, 4096), 256, 0, stream>>>(tbuf + (size_t)b * 128 * 4096, patT, 128);
        gemm(A2, patT, 128, 1152, rb1_b2, nullptr, 0, h1f + (size_t)b * 128 * 4096,
             h2f + (size_t)b * 128 * 4096, nullptr, 0);
    }

    // pyramid levels: bilinear antialias resize to 57/51/44
    const long refbs = 128L * 7786;
    d7_resize<57><<<dim3(13, 128, 2), 256, 0, stream>>>(h2f, refb, refbs);
    d7_resize<51><<<dim3(11, 128, 2), 256, 0, stream>>>(h2f, refb + 3249L * 128, refbs);
    d7_resize<44><<<dim3(8, 128, 2), 256, 0, stream>>>(h2f, refb + 5850L * 128, refbs);

    // 1x1 convs (+prelu)
    const long h2bs = 128L * 4096, mbbs = 64L * 4096, rmbs = 64L * 11882, babs = 128L * 11882;
    d7_conv1x1<<<dim3(16, 64, 2), 256, 0, stream>>>(h2f, pamb_w, pamb_b, pamb_a, mbb, 128, 4096, h2bs, mbbs);
    d7_conv1x1<<<dim3(16, 64, 2), 256, 0, stream>>>(h2f, pam_w, pam_b, pam_a, refm, 128, 4096, h2bs, rmbs);
    d7_conv1x1<<<dim3(13, 64, 2), 256, 0, stream>>>(refb, pam_w, pam_b, pam_a, refm + 4096L * 64, 128, 3249, refbs, rmbs);
    d7_conv1x1<<<dim3(11, 64, 2), 256, 0, stream>>>(refb + 3249L * 128, pam_w, pam_b, pam_a, refm + 7345L * 64, 128, 2601, refbs, rmbs);
    d7_conv1x1<<<dim3(8, 64, 2), 256, 0, stream>>>(refb + 5850L * 128, pam_w, pam_b, pam_a, refm + 9946L * 64, 128, 1936, refbs, rmbs);
    d7_conv1x1<<<dim3(16, 128, 2), 256, 0, stream>>>(h2f, paa_w, paa_b, paa_a, baseb, 128, 4096, h2bs, babs);
    d7_conv1x1<<<dim3(13, 128, 2), 256, 0, stream>>>(refb, paa_w, paa_b, paa_a, baseb + 4096L * 128, 128, 3249, refbs, babs);
    d7_conv1x1<<<dim3(11, 128, 2), 256, 0, stream>>>(refb + 3249L * 128, paa_w, paa_b, paa_a, baseb + 7345L * 128, 128, 2601, refbs, babs);
    d7_conv1x1<<<dim3(8, 128, 2), 256, 0, stream>>>(refb + 5850L * 128, paa_w, paa_b, paa_a, baseb + 9946L * 128, 128, 1936, refbs, babs);

    // attention per batch
    for (int b = 0; b < 2; ++b) {
        d7_wn<<<dim3(2976), 256, 0, stream>>>(refm + (size_t)b * rmbs, wnb);
        d7_im2col<<<dim3(3, 4096), 256, 0, stream>>>(mbb + (size_t)b * mbbs, patT, 64);
        gemm(wnb, patT, 11904, 576, nullptr, nullptr, 0, nullptr, nullptr, scT, 11904);
        d7_softmax<<<dim3(4096), 256, 0, stream>>>(scT);
        d7_rwp<<<dim3(47, 1152), 256, 0, stream>>>(baseb + (size_t)b * babs, rwpb);
        gemm(rwpb, scT, 1152, 11904, nullptr, nullptr, 0, nullptr, Qb, nullptr, 0);
        d7_shiftadd<<<dim3(16, 128), 256, 0, stream>>>(Qb, h2f + (size_t)b * h2bs, paf + (size_t)b * h2bs);
    }

    // ResBlock2 -> d_out
    for (int b = 0; b < 2; ++b) {
        d7_im2col<<<dim3(5, 4096), 256, 0, stream>>>(paf + (size_t)b * h2bs, patT, 128);
        gemm(A3, patT, 128, 1152, rb2_b1, nullptr, 2, nullptr, tbuf + (size_t)b * h2bs, nullptr, 0);
    }
    for (int b = 0; b < 2; ++b) {
        d7_im2col<<<dim3(5, 4096), 256, 0, stream>>>(tbuf + (size_t)b * h2bs, patT, 128);
        gemm(A4, patT, 128, 1152, rb2_b2, nullptr, 0, paf + (size_t)b * h2bs,
             out + (size_t)b * h2bs, nullptr, 0);
    }
}